// Round 4
// baseline (336.426 us; speedup 1.0000x reference)
//
#include <hip/hip_runtime.h>

// Spatially-varying 19x19 blur, reflect pad 9.
// out[b,c,i,j] = (1/361) * sum_{u,v} xpad[b,c,i+u,j+v] * kernel[b,u*19+v,i,j]
// x[2,3,256,256] f32, kernel[2,361,256,256] f32 (189 MB, read once -> HBM bound).
//
// R4: SAME kernel as R3 (known-correct), but launched 3x in the graph.
// Purpose: slope measurement. dur_us = harness_fixed + 3*K, so
// (dur_R4 - dur_R3)/2 = per-launch kernel duration. The kernel is idempotent
// (plain full-overwrite stores, reads only d_in), so correctness is unchanged.

#define LW     19
#define PAD    9
#define K2     361
#define HH     256
#define WW     256
#define CC     3
#define HW     (HH * WW)

#define TX     8                  // threads in x
#define TY     4                  // rows per block
#define NS     8                  // u-slices per block
#define TPW    4                  // pixels per thread (float4)
#define TILE_W (TX * TPW)         // 32
#define SM_H   (TY + LW - 1)      // 22
#define SM_W   52                 // 32+18=50, padded to 52 (208 B rows, 16B-aligned)

__global__ __launch_bounds__(256, 4)
void svblur_main(const float* __restrict__ x,
                 const float* __restrict__ ker,
                 float* __restrict__ out) {
    __shared__ float tile[CC][SM_H][SM_W];        // 3*22*52*4 = 13728 B
    __shared__ float partials[NS * 12 * 32];      // 12288 B

    const int tx  = threadIdx.x;                  // 0..7
    const int ty  = threadIdx.y;                  // 0..3
    const int s   = threadIdx.z;                  // 0..7  (u-slice)
    const int tid = s * 32 + ty * TX + tx;        // 0..255
    const int j0  = blockIdx.x * TILE_W;
    const int i0  = blockIdx.y * TY;
    const int b   = blockIdx.z;

    // ---- stage reflect-padded x rows [i0-9 .. i0+12] into LDS ----
    const float* xb = x + (size_t)b * CC * HW;
    for (int idx = tid; idx < CC * SM_H * SM_W; idx += 256) {
        int c  = idx / (SM_H * SM_W);
        int rm = idx - c * (SM_H * SM_W);
        int r  = rm / SM_W;
        int cc = rm - r * SM_W;
        int gr = i0 + r - PAD;
        gr = gr < 0 ? -gr : (gr >= HH ? 2 * HH - 2 - gr : gr);
        int gc = j0 + cc - PAD;
        gc = gc < 0 ? -gc : (gc >= WW ? 2 * WW - 2 - gc : gc);
        ((float*)tile)[idx] = xb[(c * HH + gr) * WW + gc];
    }
    __syncthreads();

    const int jt = tx * TPW;                      // 0..28 (16B-aligned in row)
    const int i  = i0 + ty;
    const int j  = j0 + jt;
    const int u0 = (s * LW) / NS;                 // slice's u range: <=3 rows
    const int u1 = ((s + 1) * LW) / NS;

    float acc[CC][TPW];
    #pragma unroll
    for (int c = 0; c < CC; ++c)
        #pragma unroll
        for (int p = 0; p < TPW; ++p) acc[c][p] = 0.f;

    for (int u = u0; u < u1; ++u) {
        // cache x window [jt .. jt+23] for halo row ty+u, all 3 channels
        float xr[CC][24];
        #pragma unroll
        for (int c = 0; c < CC; ++c) {
            const float4* rp = (const float4*)&tile[c][ty + u][jt];
            #pragma unroll
            for (int q = 0; q < 6; ++q) {
                float4 v4 = rp[q];                // ds_read_b128, aligned
                xr[c][q * 4 + 0] = v4.x;
                xr[c][q * 4 + 1] = v4.y;
                xr[c][q * 4 + 2] = v4.z;
                xr[c][q * 4 + 3] = v4.w;
            }
        }
        const float4* kp = (const float4*)(ker
            + ((size_t)(b * K2 + u * LW)) * HW + (size_t)i * WW + j);
        #pragma unroll
        for (int v = 0; v < LW; ++v) {
            float4 kv = kp[(size_t)v * (HW / 4)]; // coalesced 16B/lane
            #pragma unroll
            for (int c = 0; c < CC; ++c) {
                acc[c][0] = fmaf(xr[c][v + 0], kv.x, acc[c][0]);
                acc[c][1] = fmaf(xr[c][v + 1], kv.y, acc[c][1]);
                acc[c][2] = fmaf(xr[c][v + 2], kv.z, acc[c][2]);
                acc[c][3] = fmaf(xr[c][v + 3], kv.w, acc[c][3]);
            }
        }
    }

    // ---- LDS reduction over the 8 u-slices ----
    const int lane = ty * TX + tx;                // 0..31
    #pragma unroll
    for (int c = 0; c < CC; ++c)
        #pragma unroll
        for (int p = 0; p < TPW; ++p)
            partials[(s * 12 + c * 4 + p) * 32 + lane] = acc[c][p];  // conflict-free
    __syncthreads();

    const float sc = 1.0f / (float)K2;
    for (int r = tid; r < 12 * 32; r += 256) {
        int cp = r >> 5, ln = r & 31;
        float sum = 0.f;
        #pragma unroll
        for (int ss = 0; ss < NS; ++ss)
            sum += partials[(ss * 12 + cp) * 32 + ln];
        int c  = cp >> 2, p = cp & 3;
        int ii = i0 + (ln >> 3);
        int jj = j0 + (ln & 7) * TPW + p;
        out[((size_t)(b * CC + c) * HH + ii) * WW + jj] = sum * sc;
    }
}

extern "C" void kernel_launch(void* const* d_in, const int* in_sizes, int n_in,
                              void* d_out, int out_size, void* d_ws, size_t ws_size,
                              hipStream_t stream) {
    const float* x   = (const float*)d_in[0];   // [2,3,256,256]
    const float* ker = (const float*)d_in[1];   // [2,361,256,256]
    float* out       = (float*)d_out;           // [2,3,256,256]

    dim3 grid(WW / TILE_W, HH / TY, 2);         // (8, 64, 2) = 1024 blocks
    dim3 block(TX, TY, NS);                     // 256 threads

    // Launched 3x for slope measurement: idempotent (no atomics, no ws use,
    // every output element fully overwritten with identical values).
    svblur_main<<<grid, block, 0, stream>>>(x, ker, out);
    svblur_main<<<grid, block, 0, stream>>>(x, ker, out);
    svblur_main<<<grid, block, 0, stream>>>(x, ker, out);
}

// Round 5
// 268.785 us; speedup vs baseline: 1.2517x; 1.2517x over previous
//
#include <hip/hip_runtime.h>

// Spatially-varying 19x19 blur, reflect pad 9.
// out[b,c,i,j] = (1/361) * sum_{u,v} xpad[b,c,i+u,j+v] * kernel[b,u*19+v,i,j]
// x[2,3,256,256] f32, kernel[2,361,256,256] f32 (189 MB, read once -> HBM bound).
//
// FINAL (R3 structure, single launch). Slope measurement (R4: 3x launch) gave
// K ~= 33.4 us/launch = 5.7 TB/s effective over the 190 MB streamed -> ~90% of
// the 6.3 TB/s achievable HBM ceiling. Memory-roofline-bound; dur_us is
// dominated by ~236 us of fixed harness poison/restore work.
//
// Structure: block = (8,4,8) = 256 threads; tile 32x4 output pixels,
// 4 px/thread (float4 kernel loads, 16 B/lane, fully coalesced). The 19 u-rows
// split across 8 intra-block slices (threadIdx.z); partials reduced via LDS
// (conflict-free), single writer per output. Grid 8x64x2 = 1024 blocks =
// 4/CU exactly -> 16 waves/CU at __launch_bounds__(256,4).

#define LW     19
#define PAD    9
#define K2     361
#define HH     256
#define WW     256
#define CC     3
#define HW     (HH * WW)

#define TX     8                  // threads in x
#define TY     4                  // rows per block
#define NS     8                  // u-slices per block
#define TPW    4                  // pixels per thread (float4)
#define TILE_W (TX * TPW)         // 32
#define SM_H   (TY + LW - 1)      // 22
#define SM_W   52                 // 32+18=50, padded to 52 (208 B rows, 16B-aligned)

__global__ __launch_bounds__(256, 4)
void svblur_main(const float* __restrict__ x,
                 const float* __restrict__ ker,
                 float* __restrict__ out) {
    __shared__ float tile[CC][SM_H][SM_W];        // 3*22*52*4 = 13728 B
    __shared__ float partials[NS * 12 * 32];      // 12288 B

    const int tx  = threadIdx.x;                  // 0..7
    const int ty  = threadIdx.y;                  // 0..3
    const int s   = threadIdx.z;                  // 0..7  (u-slice)
    const int tid = s * 32 + ty * TX + tx;        // 0..255
    const int j0  = blockIdx.x * TILE_W;
    const int i0  = blockIdx.y * TY;
    const int b   = blockIdx.z;

    // ---- stage reflect-padded x rows [i0-9 .. i0+12] into LDS ----
    const float* xb = x + (size_t)b * CC * HW;
    for (int idx = tid; idx < CC * SM_H * SM_W; idx += 256) {
        int c  = idx / (SM_H * SM_W);
        int rm = idx - c * (SM_H * SM_W);
        int r  = rm / SM_W;
        int cc = rm - r * SM_W;
        int gr = i0 + r - PAD;
        gr = gr < 0 ? -gr : (gr >= HH ? 2 * HH - 2 - gr : gr);
        int gc = j0 + cc - PAD;
        gc = gc < 0 ? -gc : (gc >= WW ? 2 * WW - 2 - gc : gc);
        ((float*)tile)[idx] = xb[(c * HH + gr) * WW + gc];
    }
    __syncthreads();

    const int jt = tx * TPW;                      // 0..28 (16B-aligned in row)
    const int i  = i0 + ty;
    const int j  = j0 + jt;
    const int u0 = (s * LW) / NS;                 // slice's u range: <=3 rows
    const int u1 = ((s + 1) * LW) / NS;

    float acc[CC][TPW];
    #pragma unroll
    for (int c = 0; c < CC; ++c)
        #pragma unroll
        for (int p = 0; p < TPW; ++p) acc[c][p] = 0.f;

    for (int u = u0; u < u1; ++u) {
        // cache x window [jt .. jt+23] for halo row ty+u, all 3 channels
        float xr[CC][24];
        #pragma unroll
        for (int c = 0; c < CC; ++c) {
            const float4* rp = (const float4*)&tile[c][ty + u][jt];
            #pragma unroll
            for (int q = 0; q < 6; ++q) {
                float4 v4 = rp[q];                // ds_read_b128, aligned
                xr[c][q * 4 + 0] = v4.x;
                xr[c][q * 4 + 1] = v4.y;
                xr[c][q * 4 + 2] = v4.z;
                xr[c][q * 4 + 3] = v4.w;
            }
        }
        const float4* kp = (const float4*)(ker
            + ((size_t)(b * K2 + u * LW)) * HW + (size_t)i * WW + j);
        #pragma unroll
        for (int v = 0; v < LW; ++v) {
            float4 kv = kp[(size_t)v * (HW / 4)]; // coalesced 16B/lane
            #pragma unroll
            for (int c = 0; c < CC; ++c) {
                acc[c][0] = fmaf(xr[c][v + 0], kv.x, acc[c][0]);
                acc[c][1] = fmaf(xr[c][v + 1], kv.y, acc[c][1]);
                acc[c][2] = fmaf(xr[c][v + 2], kv.z, acc[c][2]);
                acc[c][3] = fmaf(xr[c][v + 3], kv.w, acc[c][3]);
            }
        }
    }

    // ---- LDS reduction over the 8 u-slices ----
    const int lane = ty * TX + tx;                // 0..31
    #pragma unroll
    for (int c = 0; c < CC; ++c)
        #pragma unroll
        for (int p = 0; p < TPW; ++p)
            partials[(s * 12 + c * 4 + p) * 32 + lane] = acc[c][p];  // conflict-free
    __syncthreads();

    const float sc = 1.0f / (float)K2;
    for (int r = tid; r < 12 * 32; r += 256) {
        int cp = r >> 5, ln = r & 31;
        float sum = 0.f;
        #pragma unroll
        for (int ss = 0; ss < NS; ++ss)
            sum += partials[(ss * 12 + cp) * 32 + ln];
        int c  = cp >> 2, p = cp & 3;
        int ii = i0 + (ln >> 3);
        int jj = j0 + (ln & 7) * TPW + p;
        out[((size_t)(b * CC + c) * HH + ii) * WW + jj] = sum * sc;
    }
}

extern "C" void kernel_launch(void* const* d_in, const int* in_sizes, int n_in,
                              void* d_out, int out_size, void* d_ws, size_t ws_size,
                              hipStream_t stream) {
    const float* x   = (const float*)d_in[0];   // [2,3,256,256]
    const float* ker = (const float*)d_in[1];   // [2,361,256,256]
    float* out       = (float*)d_out;           // [2,3,256,256]

    dim3 grid(WW / TILE_W, HH / TY, 2);         // (8, 64, 2) = 1024 blocks
    dim3 block(TX, TY, NS);                     // 256 threads
    svblur_main<<<grid, block, 0, stream>>>(x, ker, out);
}